// Round 1
// baseline (529.876 us; speedup 1.0000x reference)
//
#include <hip/hip_runtime.h>

#define BB 32
#define NN 300
#define HH 1024
#define WW 1024
#define SEGR 64
#define NSEG 16  // HH / SEGR

// Kernel 1: fused row-scan + segmented column accumulation.
// Block = 256 threads, each owns 4 consecutive columns. One block per
// (batch, 64-row segment). Computes inclusive 2D integral of
// g = seg[class2] - seg[class1] *within the segment*, plus per-segment
// column totals for the later cross-segment scan.
__global__ __launch_bounds__(256) void integral_kernel(
    const float* __restrict__ seg, float* __restrict__ I, size_t ibstride,
    float* __restrict__ segT)
{
    int blk  = blockIdx.x;
    int b    = blk >> 4;     // / NSEG
    int s    = blk & 15;     // % NSEG
    int t    = threadIdx.x;
    int lane = t & 63;
    int warp = t >> 6;
    int c0   = t * 4;
    int row0 = s * SEGR;

    const float* p1 = seg + ((size_t)b * 3 + 1) * ((size_t)HH * WW);
    const float* p2 = seg + ((size_t)b * 3 + 2) * ((size_t)HH * WW);
    float* Ib = I + (size_t)b * ibstride;

    __shared__ float wsum[2][4];

    float acc0 = 0.f, acc1 = 0.f, acc2 = 0.f, acc3 = 0.f;

    // prefetch first row
    float4 f1 = *(const float4*)(p1 + (size_t)row0 * WW + c0);
    float4 f2 = *(const float4*)(p2 + (size_t)row0 * WW + c0);

    for (int y = 0; y < SEGR; ++y) {
        int row = row0 + y;
        float4 cf1 = f1, cf2 = f2;
        if (y + 1 < SEGR) {
            f1 = *(const float4*)(p1 + (size_t)(row + 1) * WW + c0);
            f2 = *(const float4*)(p2 + (size_t)(row + 1) * WW + c0);
        }
        float d0 = cf2.x - cf1.x;
        float d1 = cf2.y - cf1.y;
        float d2 = cf2.z - cf1.z;
        float d3 = cf2.w - cf1.w;
        float l1 = d0 + d1;
        float l2 = l1 + d2;
        float l3 = l2 + d3;

        // inclusive wave scan of per-thread totals (wave = 64 lanes)
        float incl = l3;
        #pragma unroll
        for (int d = 1; d < 64; d <<= 1) {
            float v = __shfl_up(incl, d, 64);
            if (lane >= d) incl += v;
        }
        int p = y & 1;  // double-buffered LDS -> one barrier per row is safe
        if (lane == 63) wsum[p][warp] = incl;
        __syncthreads();
        float base = incl - l3;  // exclusive within wave
        #pragma unroll
        for (int w = 0; w < 3; ++w)
            if (warp > w) base += wsum[p][w];

        acc0 += base + d0;
        acc1 += base + l1;
        acc2 += base + l2;
        acc3 += base + l3;

        *(float4*)(Ib + (size_t)row * WW + c0) =
            make_float4(acc0, acc1, acc2, acc3);
    }
    // per-segment column totals
    *(float4*)(segT + (size_t)(b * NSEG + s) * WW + c0) =
        make_float4(acc0, acc1, acc2, acc3);
}

// Kernel 2: exclusive scan over the 16 segment totals, per (batch, column).
__global__ __launch_bounds__(256) void segscan_kernel(
    const float* __restrict__ segT, float* __restrict__ offs)
{
    int idx = blockIdx.x * blockDim.x + threadIdx.x;  // over BB*WW
    int b = idx >> 10;
    int x = idx & 1023;
    float run = 0.f;
    #pragma unroll
    for (int s = 0; s < NSEG; ++s) {
        size_t o = (size_t)(b * NSEG + s) * WW + x;
        float v = segT[o];
        offs[o] = run;
        run += v;
    }
}

// Kernel 3: per-box corner gather + reduction.
__global__ __launch_bounds__(256) void gather_kernel(
    const float4* __restrict__ boxes, const float* __restrict__ conf,
    const float* __restrict__ I, size_t ibstride,
    const float* __restrict__ offs, float* __restrict__ out)
{
    int gid = blockIdx.x * blockDim.x + threadIdx.x;
    float local = 0.f;
    if (gid < BB * NN) {
        int b = gid / NN;
        float4 box = boxes[gid];
        float c = conf[gid];
        float cx = box.x, cy = box.y, w = box.z, h = box.w;
        // bit-exact replication of reference fp32 index math (x1024 is exact)
        float x1f = (cx - 0.5f * w) * (float)WW;
        float x2f = (cx + 0.5f * w) * (float)WW;
        float y1f = (cy - 0.5f * h) * (float)HH;
        float y2f = (cy + 0.5f * h) * (float)HH;
        int x1 = min(max((int)truncf(x1f), 0), WW - 1);
        int x2 = min(max((int)truncf(x2f), 0), WW - 1);
        int y1 = min(max((int)truncf(y1f), 0), HH - 1);
        int y2 = min(max((int)truncf(y2f), 0), HH - 1);
        bool valid = (c >= 0.3f) && (x2 > x1) && (y2 > y1);
        if (valid) {
            const float* Ib = I + (size_t)b * ibstride;
            const float* Ob = offs + (size_t)b * (NSEG * WW);
            auto corner = [&](int y, int x) -> float {
                if (y == 0 || x == 0) return 0.f;
                int yy = y - 1, xx = x - 1;
                return Ib[(size_t)yy * WW + xx] + Ob[(yy >> 6) * WW + xx];
            };
            float sum = corner(y2, x2) - corner(y1, x2)
                      - corner(y2, x1) + corner(y1, x1);
            float area = (float)((y2 - y1) * (x2 - x1));
            local = fmaxf(sum / area, 0.f) * c;
        }
    }
    // wave reduce (64-lane)
    #pragma unroll
    for (int d = 32; d > 0; d >>= 1)
        local += __shfl_down(local, d, 64);
    __shared__ float blksum[4];
    int lane = threadIdx.x & 63, warp = threadIdx.x >> 6;
    if (lane == 0) blksum[warp] = local;
    __syncthreads();
    if (threadIdx.x == 0) {
        float t = blksum[0] + blksum[1] + blksum[2] + blksum[3];
        atomicAdd(out, t * (1.0f / (BB * NN)));
    }
}

extern "C" void kernel_launch(void* const* d_in, const int* in_sizes, int n_in,
                              void* d_out, int out_size, void* d_ws, size_t ws_size,
                              hipStream_t stream) {
    const float* boxes = (const float*)d_in[0];   // (32,300,4)
    const float* conf  = (const float*)d_in[1];   // (32,300)
    const float* seg   = (const float*)d_in[2];   // (32,3,1024,1024)
    float* out = (float*)d_out;

    const size_t i_bytes   = (size_t)BB * HH * WW * sizeof(float);      // 128 MiB
    const size_t aux_elems = (size_t)BB * NSEG * WW;                    // 512K floats
    const size_t aux_bytes = aux_elems * sizeof(float);                 // 2 MiB

    float* I;
    size_t ibstride;
    float* segT;
    float* offs;
    if (ws_size >= i_bytes + 2 * aux_bytes) {
        I        = (float*)d_ws;
        ibstride = (size_t)HH * WW;
        segT     = (float*)((char*)d_ws + i_bytes);
        offs     = segT + aux_elems;
    } else {
        // Fallback: store I in the unused class-0 planes of the input.
        // (Harness restores d_in from pristine before every launch.)
        I        = (float*)d_in[2];
        ibstride = (size_t)3 * HH * WW;
        segT     = (float*)d_ws;
        offs     = segT + aux_elems;
    }

    hipMemsetAsync(d_out, 0, sizeof(float), stream);
    integral_kernel<<<BB * NSEG, 256, 0, stream>>>(seg, I, ibstride, segT);
    segscan_kernel<<<(BB * WW) / 256, 256, 0, stream>>>(segT, offs);
    gather_kernel<<<(BB * NN + 255) / 256, 256, 0, stream>>>(
        (const float4*)boxes, conf, I, ibstride, offs, out);
}

// Round 2
// 516.048 us; speedup vs baseline: 1.0268x; 1.0268x over previous
//
#include <hip/hip_runtime.h>

#define BB 32
#define NN 300
#define HH 1024
#define WW 1024
#define RSTRIP 8                 // rows per block strip
#define NSTRIP (HH / RSTRIP)     // 128 strips per batch

// One block per (batch, 8-row strip). Each wave computes inclusive row
// prefixes of g = seg[cls2] - seg[cls1] for 2 rows (16 elems/lane), parks
// them in LDS, then the block resolves all 300 boxes of its batch against
// the strip and atomically accumulates per-box partial sums.
__global__ __launch_bounds__(256) void strip_kernel(
    const float* __restrict__ seg,
    const float4* __restrict__ boxes,
    const float* __restrict__ conf,
    float* __restrict__ boxacc)
{
    int blk  = blockIdx.x;
    int b    = blk >> 7;         // / NSTRIP
    int s    = blk & (NSTRIP - 1);
    int r0   = s * RSTRIP;
    int t    = threadIdx.x;
    int lane = t & 63;
    int warp = t >> 6;

    __shared__ float L[RSTRIP][WW];

    const float* p1 = seg + ((size_t)b * 3 + 1) * ((size_t)HH * WW);
    const float* p2 = seg + ((size_t)b * 3 + 2) * ((size_t)HH * WW);

    // Two rows per wave: rows r0 + warp and r0 + 4 + warp.
    int row0 = r0 + warp;
    int row1 = r0 + 4 + warp;
    const float* q1a = p1 + (size_t)row0 * WW + lane * 16;
    const float* q2a = p2 + (size_t)row0 * WW + lane * 16;
    const float* q1b = p1 + (size_t)row1 * WW + lane * 16;
    const float* q2b = p2 + (size_t)row1 * WW + lane * 16;

    // Issue all 16 loads up front for MLP.
    float4 a0 = *(const float4*)(q1a +  0), a1 = *(const float4*)(q1a +  4);
    float4 a2 = *(const float4*)(q1a +  8), a3 = *(const float4*)(q1a + 12);
    float4 c0 = *(const float4*)(q2a +  0), c1 = *(const float4*)(q2a +  4);
    float4 c2 = *(const float4*)(q2a +  8), c3 = *(const float4*)(q2a + 12);
    float4 d0 = *(const float4*)(q1b +  0), d1 = *(const float4*)(q1b +  4);
    float4 d2 = *(const float4*)(q1b +  8), d3 = *(const float4*)(q1b + 12);
    float4 e0 = *(const float4*)(q2b +  0), e1 = *(const float4*)(q2b +  4);
    float4 e2 = *(const float4*)(q2b +  8), e3 = *(const float4*)(q2b + 12);

    #pragma unroll
    for (int rr = 0; rr < 2; ++rr) {
        float g[16];
        if (rr == 0) {
            g[ 0]=c0.x-a0.x; g[ 1]=c0.y-a0.y; g[ 2]=c0.z-a0.z; g[ 3]=c0.w-a0.w;
            g[ 4]=c1.x-a1.x; g[ 5]=c1.y-a1.y; g[ 6]=c1.z-a1.z; g[ 7]=c1.w-a1.w;
            g[ 8]=c2.x-a2.x; g[ 9]=c2.y-a2.y; g[10]=c2.z-a2.z; g[11]=c2.w-a2.w;
            g[12]=c3.x-a3.x; g[13]=c3.y-a3.y; g[14]=c3.z-a3.z; g[15]=c3.w-a3.w;
        } else {
            g[ 0]=e0.x-d0.x; g[ 1]=e0.y-d0.y; g[ 2]=e0.z-d0.z; g[ 3]=e0.w-d0.w;
            g[ 4]=e1.x-d1.x; g[ 5]=e1.y-d1.y; g[ 6]=e1.z-d1.z; g[ 7]=e1.w-d1.w;
            g[ 8]=e2.x-d2.x; g[ 9]=e2.y-d2.y; g[10]=e2.z-d2.z; g[11]=e2.w-d2.w;
            g[12]=e3.x-d3.x; g[13]=e3.y-d3.y; g[14]=e3.z-d3.z; g[15]=e3.w-d3.w;
        }
        // sequential inclusive prefix over the lane's 16 elements
        float run = 0.f;
        #pragma unroll
        for (int j = 0; j < 16; ++j) { run += g[j]; g[j] = run; }
        // wave-wide exclusive scan of lane totals
        float incl = run;
        #pragma unroll
        for (int d = 1; d < 64; d <<= 1) {
            float v = __shfl_up(incl, d, 64);
            if (lane >= d) incl += v;
        }
        float base = incl - run;
        int r = (rr == 0 ? warp : 4 + warp);
        float* Lr = &L[r][lane * 16];
        *(float4*)(Lr +  0) = make_float4(g[ 0]+base, g[ 1]+base, g[ 2]+base, g[ 3]+base);
        *(float4*)(Lr +  4) = make_float4(g[ 4]+base, g[ 5]+base, g[ 6]+base, g[ 7]+base);
        *(float4*)(Lr +  8) = make_float4(g[ 8]+base, g[ 9]+base, g[10]+base, g[11]+base);
        *(float4*)(Lr + 12) = make_float4(g[12]+base, g[13]+base, g[14]+base, g[15]+base);
    }
    __syncthreads();

    // Box phase: resolve this batch's boxes against rows [r0, r0+7].
    for (int n = t; n < NN; n += 256) {
        int gi = b * NN + n;
        float4 bx = boxes[gi];
        float cf  = conf[gi];
        float x1f = (bx.x - 0.5f * bx.z) * (float)WW;
        float x2f = (bx.x + 0.5f * bx.z) * (float)WW;
        float y1f = (bx.y - 0.5f * bx.w) * (float)HH;
        float y2f = (bx.y + 0.5f * bx.w) * (float)HH;
        int x1 = min(max((int)truncf(x1f), 0), WW - 1);
        int x2 = min(max((int)truncf(x2f), 0), WW - 1);
        int y1 = min(max((int)truncf(y1f), 0), HH - 1);
        int y2 = min(max((int)truncf(y2f), 0), HH - 1);
        if (!((cf >= 0.3f) && (x2 > x1) && (y2 > y1))) continue;
        int lo = max(y1, r0);
        int hi = min(y2 - 1, r0 + RSTRIP - 1);
        if (lo > hi) continue;
        int xa = x2 - 1;
        int xb = x1 - 1;   // may be -1 -> contributes 0
        float sum = 0.f;
        for (int r = lo; r <= hi; ++r) {
            float v = L[r - r0][xa];
            if (xb >= 0) v -= L[r - r0][xb];
            sum += v;
        }
        atomicAdd(&boxacc[gi], sum);
    }
}

// Finalize: relu((fsum-dsum)/area)*conf, mean over B*N. Single block.
__global__ __launch_bounds__(256) void finalize_kernel(
    const float4* __restrict__ boxes,
    const float* __restrict__ conf,
    const float* __restrict__ boxacc,
    float* __restrict__ out)
{
    int t = threadIdx.x;
    float local = 0.f;
    for (int i = t; i < BB * NN; i += 256) {
        float4 bx = boxes[i];
        float cf  = conf[i];
        float x1f = (bx.x - 0.5f * bx.z) * (float)WW;
        float x2f = (bx.x + 0.5f * bx.z) * (float)WW;
        float y1f = (bx.y - 0.5f * bx.w) * (float)HH;
        float y2f = (bx.y + 0.5f * bx.w) * (float)HH;
        int x1 = min(max((int)truncf(x1f), 0), WW - 1);
        int x2 = min(max((int)truncf(x2f), 0), WW - 1);
        int y1 = min(max((int)truncf(y1f), 0), HH - 1);
        int y2 = min(max((int)truncf(y2f), 0), HH - 1);
        if ((cf >= 0.3f) && (x2 > x1) && (y2 > y1)) {
            float area = (float)((y2 - y1) * (x2 - x1));
            local += fmaxf(boxacc[i] / area, 0.f) * cf;
        }
    }
    #pragma unroll
    for (int d = 32; d > 0; d >>= 1)
        local += __shfl_down(local, d, 64);
    __shared__ float bsum[4];
    int lane = t & 63, warp = t >> 6;
    if (lane == 0) bsum[warp] = local;
    __syncthreads();
    if (t == 0)
        out[0] = (bsum[0] + bsum[1] + bsum[2] + bsum[3]) * (1.0f / (BB * NN));
}

extern "C" void kernel_launch(void* const* d_in, const int* in_sizes, int n_in,
                              void* d_out, int out_size, void* d_ws, size_t ws_size,
                              hipStream_t stream) {
    const float4* boxes = (const float4*)d_in[0];  // (32,300,4)
    const float*  conf  = (const float*)d_in[1];   // (32,300)
    const float*  seg   = (const float*)d_in[2];   // (32,3,1024,1024)
    float* out    = (float*)d_out;
    float* boxacc = (float*)d_ws;                  // 9600 floats

    hipMemsetAsync(boxacc, 0, (size_t)BB * NN * sizeof(float), stream);
    strip_kernel<<<BB * NSTRIP, 256, 0, stream>>>(seg, boxes, conf, boxacc);
    finalize_kernel<<<1, 256, 0, stream>>>(boxes, conf, boxacc, out);
}

// Round 3
// 496.926 us; speedup vs baseline: 1.0663x; 1.0385x over previous
//
#include <hip/hip_runtime.h>

#define BB 32
#define NN 300
#define HH 1024
#define WW 1024
#define RSTRIP 8                 // rows per block strip
#define NSTRIP (HH / RSTRIP)     // 128 strips per batch

// One block per (batch, 8-row strip); 512 threads = 8 waves, one row per
// wave (16 cols/lane). Row-wise inclusive prefix of g = seg[2] - seg[1]
// parked in 32 KiB LDS, then each of the 300 boxes of the batch is resolved
// by one thread against the strip and accumulated via one atomicAdd.
// __launch_bounds__(512,8): cap 64 VGPR -> 4 blocks/CU = 32 waves/CU (full).
__global__ __launch_bounds__(512, 8) void strip_kernel(
    const float* __restrict__ seg,
    const float4* __restrict__ boxes,
    const float* __restrict__ conf,
    float* __restrict__ boxacc)
{
    int blk  = blockIdx.x;
    int b    = blk >> 7;          // / NSTRIP
    int s    = blk & (NSTRIP - 1);
    int r0   = s * RSTRIP;
    int t    = threadIdx.x;
    int lane = t & 63;
    int warp = t >> 6;            // 0..7 -> row within strip

    __shared__ float L[RSTRIP][WW];

    const float* p1 = seg + ((size_t)b * 3 + 1) * ((size_t)HH * WW);
    const float* p2 = seg + ((size_t)b * 3 + 2) * ((size_t)HH * WW);
    const float* q1 = p1 + (size_t)(r0 + warp) * WW + lane * 16;
    const float* q2 = p2 + (size_t)(r0 + warp) * WW + lane * 16;

    // Box metadata load issued early to overlap with the streaming loads.
    bool hasbox = t < NN;
    float4 bx = make_float4(0.f, 0.f, 0.f, 0.f);
    float cf = 0.f;
    if (hasbox) { bx = boxes[b * NN + t]; cf = conf[b * NN + t]; }

    float4 u0 = *(const float4*)(q2 +  0), v0 = *(const float4*)(q1 +  0);
    float4 u1 = *(const float4*)(q2 +  4), v1 = *(const float4*)(q1 +  4);
    float4 u2 = *(const float4*)(q2 +  8), v2 = *(const float4*)(q1 +  8);
    float4 u3 = *(const float4*)(q2 + 12), v3 = *(const float4*)(q1 + 12);

    float g[16];
    g[ 0]=u0.x-v0.x; g[ 1]=u0.y-v0.y; g[ 2]=u0.z-v0.z; g[ 3]=u0.w-v0.w;
    g[ 4]=u1.x-v1.x; g[ 5]=u1.y-v1.y; g[ 6]=u1.z-v1.z; g[ 7]=u1.w-v1.w;
    g[ 8]=u2.x-v2.x; g[ 9]=u2.y-v2.y; g[10]=u2.z-v2.z; g[11]=u2.w-v2.w;
    g[12]=u3.x-v3.x; g[13]=u3.y-v3.y; g[14]=u3.z-v3.z; g[15]=u3.w-v3.w;

    // sequential inclusive prefix over the lane's 16 elements
    float run = 0.f;
    #pragma unroll
    for (int j = 0; j < 16; ++j) { run += g[j]; g[j] = run; }
    // wave-wide exclusive scan of lane totals (wave = 64 lanes)
    float incl = run;
    #pragma unroll
    for (int d = 1; d < 64; d <<= 1) {
        float v = __shfl_up(incl, d, 64);
        if (lane >= d) incl += v;
    }
    float base = incl - run;
    float* Lr = &L[warp][lane * 16];
    *(float4*)(Lr +  0) = make_float4(g[ 0]+base, g[ 1]+base, g[ 2]+base, g[ 3]+base);
    *(float4*)(Lr +  4) = make_float4(g[ 4]+base, g[ 5]+base, g[ 6]+base, g[ 7]+base);
    *(float4*)(Lr +  8) = make_float4(g[ 8]+base, g[ 9]+base, g[10]+base, g[11]+base);
    *(float4*)(Lr + 12) = make_float4(g[12]+base, g[13]+base, g[14]+base, g[15]+base);
    __syncthreads();

    // Box phase: one box per thread (300 < 512).
    if (hasbox) {
        float x1f = (bx.x - 0.5f * bx.z) * (float)WW;
        float x2f = (bx.x + 0.5f * bx.z) * (float)WW;
        float y1f = (bx.y - 0.5f * bx.w) * (float)HH;
        float y2f = (bx.y + 0.5f * bx.w) * (float)HH;
        int x1 = min(max((int)truncf(x1f), 0), WW - 1);
        int x2 = min(max((int)truncf(x2f), 0), WW - 1);
        int y1 = min(max((int)truncf(y1f), 0), HH - 1);
        int y2 = min(max((int)truncf(y2f), 0), HH - 1);
        if ((cf >= 0.3f) && (x2 > x1) && (y2 > y1)) {
            int lo = max(y1, r0);
            int hi = min(y2 - 1, r0 + RSTRIP - 1);
            if (lo <= hi) {
                int xa = x2 - 1;
                int xb = x1 - 1;   // may be -1 -> contributes 0
                float sum = 0.f;
                for (int r = lo; r <= hi; ++r) {
                    float v = L[r - r0][xa];
                    if (xb >= 0) v -= L[r - r0][xb];
                    sum += v;
                }
                atomicAdd(&boxacc[b * NN + t], sum);
            }
        }
    }
}

// Finalize: relu((fsum-dsum)/area)*conf, mean over B*N. Multi-block,
// one atomic per block into the (pre-zeroed) output.
__global__ __launch_bounds__(256) void finalize_kernel(
    const float4* __restrict__ boxes,
    const float* __restrict__ conf,
    const float* __restrict__ boxacc,
    float* __restrict__ out)
{
    int i = blockIdx.x * 256 + threadIdx.x;
    float local = 0.f;
    if (i < BB * NN) {
        float4 bx = boxes[i];
        float cf  = conf[i];
        float x1f = (bx.x - 0.5f * bx.z) * (float)WW;
        float x2f = (bx.x + 0.5f * bx.z) * (float)WW;
        float y1f = (bx.y - 0.5f * bx.w) * (float)HH;
        float y2f = (bx.y + 0.5f * bx.w) * (float)HH;
        int x1 = min(max((int)truncf(x1f), 0), WW - 1);
        int x2 = min(max((int)truncf(x2f), 0), WW - 1);
        int y1 = min(max((int)truncf(y1f), 0), HH - 1);
        int y2 = min(max((int)truncf(y2f), 0), HH - 1);
        if ((cf >= 0.3f) && (x2 > x1) && (y2 > y1)) {
            float area = (float)((y2 - y1) * (x2 - x1));
            local = fmaxf(boxacc[i] / area, 0.f) * cf;
        }
    }
    #pragma unroll
    for (int d = 32; d > 0; d >>= 1)
        local += __shfl_down(local, d, 64);
    __shared__ float bsum[4];
    int lane = threadIdx.x & 63, warp = threadIdx.x >> 6;
    if (lane == 0) bsum[warp] = local;
    __syncthreads();
    if (threadIdx.x == 0) {
        float tsum = bsum[0] + bsum[1] + bsum[2] + bsum[3];
        atomicAdd(out, tsum * (1.0f / (BB * NN)));
    }
}

extern "C" void kernel_launch(void* const* d_in, const int* in_sizes, int n_in,
                              void* d_out, int out_size, void* d_ws, size_t ws_size,
                              hipStream_t stream) {
    const float4* boxes = (const float4*)d_in[0];  // (32,300,4)
    const float*  conf  = (const float*)d_in[1];   // (32,300)
    const float*  seg   = (const float*)d_in[2];   // (32,3,1024,1024)
    float* out    = (float*)d_out;
    float* boxacc = (float*)d_ws;                  // 9600 floats

    hipMemsetAsync(boxacc, 0, (size_t)BB * NN * sizeof(float), stream);
    hipMemsetAsync(out, 0, sizeof(float), stream);
    strip_kernel<<<BB * NSTRIP, 512, 0, stream>>>(seg, boxes, conf, boxacc);
    finalize_kernel<<<(BB * NN + 255) / 256, 256, 0, stream>>>(boxes, conf, boxacc, out);
}